// Round 5
// baseline (81.123 us; speedup 1.0000x reference)
//
#include <hip/hip_runtime.h>
#include <math.h>

#define HDIM   512
#define NH     32
#define NP     16                 // mode pairs
#define LLEN   8192
#define BLOCK  256
#define LSPLIT 2
#define LPB    (LLEN / LSPLIT)    // 4096 l per block
#define LPT    16                 // consecutive l per thread

typedef float vf2 __attribute__((ext_vector_type(2)));
#define VFMA(a, b, c) __builtin_elementwise_fma((a), (b), (c))

// Grid (LSPLIT, HDIM). Thread tid owns l in [ls*LPB + 16*tid, +16).
// y_l = Re(2Cs w^l) obeys y_{l+2} = p2*y_l - q2*y_{l-2} (p2=2(wr^2-wi^2),
// q2=|w|^4): even/odd chains decouple. Modes processed in PACKED pairs
// (ext_vector float2 -> v_pk_fma_f32): 1 pk-mul + 1 pk-fma advances 2 modes.
// tabA has 2*C_scaled folded in (fp64-built), so y0 = Re(A'.B) directly.
__global__ __launch_bounds__(BLOCK) void s4d_kernel(
    const float* __restrict__ C,          // (H, NH, 2)
    const float* __restrict__ log_dt,     // (H,)
    const float* __restrict__ log_A_real, // (H, NH)
    const float* __restrict__ A_imag,     // (H, NH)
    float* __restrict__ out)              // (H, LLEN)
{
    __shared__ float4 tabA[NP][16];   // {Axa,Axb,Aya,Ayb}: 2Cs*exp(dtA*16lo)
    __shared__ float4 tabB[NP][16];   // {Bxa,Bxb,Bya,Byb}: exp(dtA*(LPB*ls+256hi))
    __shared__ float4 s_w [NP];       // {wra,wrb,wia,wib}
    __shared__ float4 s_pq[NP];       // {pa,pb,qa,qb}
    __shared__ float4 s_p2[NP];       // {p2a,p2b,q2a,q2b}

    const int h   = blockIdx.y;
    const int ls  = blockIdx.x;
    const int tid = threadIdx.x;

    // ---------------- prep (fp64): packed tables + constants ----------------
    {
        const int n = tid & 31;
        const int g = tid >> 5;            // 0..3 -> tabA, 4..7 -> tabB
        const int P = n >> 1, o = n & 1;
        const double dt  = exp((double)log_dt[h]);
        const double Are = -exp((double)log_A_real[h * NH + n]);
        const double Aim = (double)A_imag[h * NH + n];
        const double dre = Are * dt, dim = Aim * dt;

        double s1, c1; sincos(dim, &s1, &c1);
        const double em  = exp(dre);
        const double w1r = em * c1, w1i = em * s1;

        float* tabAf = (float*)&tabA[0][0];
        float* tabBf = (float*)&tabB[0][0];

        if (g < 4) {
            // 2*C_scaled (fp64)
            const double nre = w1r - 1.0, nim = w1i;
            const double den = Are * Are + Aim * Aim;
            const double fre = (nre * Are + nim * Aim) / den;
            const double fim = (nim * Are - nre * Aim) / den;
            const double Cre = (double)C[(h * NH + n) * 2 + 0];
            const double Cim = (double)C[(h * NH + n) * 2 + 1];
            const double csr = 2.0 * (Cre * fre - Cim * fim);
            const double csi = 2.0 * (Cre * fim + Cim * fre);

            const int    i0   = g * 4;
            const double base = 16.0 * (double)i0;
            double s0, c0; sincos(dim * base, &s0, &c0);
            const double m0 = exp(dre * base);
            const double er = m0 * c0, ei = m0 * s0;
            double gr = csr * er - csi * ei;
            double gi = csr * ei + csi * er;
            double ss, cs; sincos(dim * 16.0, &ss, &cs);
            const double ms  = exp(dre * 16.0);
            const double str = ms * cs, sti = ms * ss;
            for (int k = 0; k < 4; ++k) {
                const int idx = (P * 16 + i0 + k) * 4;
                tabAf[idx + o]     = (float)gr;
                tabAf[idx + 2 + o] = (float)gi;
                const double t = gr * str - gi * sti;
                gi = gr * sti + gi * str;
                gr = t;
            }
        } else {
            const int    i0   = (g - 4) * 4;
            const double base = (double)(LPB * ls) + 256.0 * (double)i0;
            double s0, c0; sincos(dim * base, &s0, &c0);
            const double m0 = exp(dre * base);
            double er = m0 * c0, ei = m0 * s0;
            double ss, cs; sincos(dim * 256.0, &ss, &cs);
            const double ms  = exp(dre * 256.0);
            const double str = ms * cs, sti = ms * ss;
            for (int k = 0; k < 4; ++k) {
                const int idx = (P * 16 + i0 + k) * 4;
                tabBf[idx + o]     = (float)er;
                tabBf[idx + 2 + o] = (float)ei;
                const double t = er * str - ei * sti;
                ei = er * sti + ei * str;
                er = t;
            }
        }

        if (g == 0) {
            float* wf  = (float*)&s_w[0];
            float* pqf = (float*)&s_pq[0];
            float* p2f = (float*)&s_p2[0];
            const double p  = 2.0 * w1r;
            const double q  = em * em;
            const double p2 = 2.0 * (w1r * w1r - w1i * w1i);
            const double q2 = q * q;
            wf [P * 4 + o]     = (float)w1r;
            wf [P * 4 + 2 + o] = (float)w1i;
            pqf[P * 4 + o]     = (float)p;
            pqf[P * 4 + 2 + o] = (float)q;
            p2f[P * 4 + o]     = (float)p2;
            p2f[P * 4 + 2 + o] = (float)q2;
        }
    }
    __syncthreads();

    const int lo = tid & 15, hi = tid >> 4;   // 16*tid = 256*hi + 16*lo

    vf2 acc[LPT];
#pragma unroll
    for (int l = 0; l < LPT; ++l) acc[l] = (vf2)(0.f);

#pragma unroll 2
    for (int P = 0; P < NP; ++P) {
        const float4 a4  = tabA[P][lo];
        const float4 b4  = tabB[P][hi];
        const float4 w4  = s_w[P];
        const float4 pq4 = s_pq[P];
        const float4 p24 = s_p2[P];

        const vf2 Ax = {a4.x, a4.y}, Ay = {a4.z, a4.w};
        const vf2 Bx = {b4.x, b4.y}, By = {b4.z, b4.w};
        const vf2 wr = {w4.x, w4.y}, wi = {w4.z, w4.w};
        const vf2 p  = {pq4.x, pq4.y}, q  = {pq4.z, pq4.w};
        const vf2 p2 = {p24.x, p24.y}, q2 = {p24.z, p24.w};

        // T = A'.B ;  y0 = Re(T) ;  y1 = Re(T*w)
        const vf2 Tr = VFMA(Ax, Bx, -(Ay * By));
        const vf2 Ti = VFMA(Ax, By,  (Ay * Bx));
        const vf2 y0 = Tr;
        const vf2 y1 = VFMA(Tr, wr, -(Ti * wi));
        const vf2 y2 = VFMA(p, y1, -(q * y0));
        const vf2 y3 = VFMA(p, y2, -(q * y1));
        acc[0] += y0; acc[1] += y1; acc[2] += y2; acc[3] += y3;

        vf2 e0 = y0, e1 = y2, o0 = y1, o1 = y3;
#pragma unroll
        for (int m = 0; m < 6; ++m) {
            const vf2 e2 = VFMA(p2, e1, -(q2 * e0));
            const vf2 o2 = VFMA(p2, o1, -(q2 * o0));
            acc[4 + 2 * m] += e2;
            acc[5 + 2 * m] += o2;
            e0 = e1; e1 = e2;
            o0 = o1; o1 = o2;
        }
    }

    // epilogue: horizontal add over the mode-pair lanes
    float* orow = out + (size_t)h * LLEN + ls * LPB + LPT * tid;
#pragma unroll
    for (int j = 0; j < 4; ++j) {
        *(float4*)(orow + 4 * j) = make_float4(
            acc[4*j+0].x + acc[4*j+0].y,
            acc[4*j+1].x + acc[4*j+1].y,
            acc[4*j+2].x + acc[4*j+2].y,
            acc[4*j+3].x + acc[4*j+3].y);
    }
}

extern "C" void kernel_launch(void* const* d_in, const int* in_sizes, int n_in,
                              void* d_out, int out_size, void* d_ws, size_t ws_size,
                              hipStream_t stream) {
    const float* C          = (const float*)d_in[0];
    const float* log_dt     = (const float*)d_in[1];
    const float* log_A_real = (const float*)d_in[2];
    const float* A_imag     = (const float*)d_in[3];
    float* out = (float*)d_out;

    dim3 grid(LSPLIT, HDIM);
    s4d_kernel<<<grid, BLOCK, 0, stream>>>(C, log_dt, log_A_real, A_imag, out);
}